// Round 3
// baseline (192.949 us; speedup 1.0000x reference)
//
#include <hip/hip_runtime.h>
#include <hip/hip_bf16.h>

typedef unsigned short u16;
typedef __bf16 bf16x8 __attribute__((ext_vector_type(8)));
typedef float f32x4 __attribute__((ext_vector_type(4)));

#define MARGIN 0.2f
#define NEG_INF -3.0e38f
#define POS_INF 3.0e38f

__device__ __forceinline__ u16 f2bf_rne(float f) {
  unsigned u = __builtin_bit_cast(unsigned, f);
  u += 0x7FFFu + ((u >> 16) & 1u);
  return (u16)(u >> 16);
}

// ---------------- prep: fp32 -> bf16 copies + row sum-of-squares ----------------
// block = 256 threads = 4 rows x 64 lanes; grid = (N/4, 3)
__global__ void prep_kernel(const float* __restrict__ A, const float* __restrict__ P,
                            const float* __restrict__ Ng,
                            u16* __restrict__ Ab, u16* __restrict__ Pb, u16* __restrict__ Nb,
                            float* __restrict__ an, float* __restrict__ pn, float* __restrict__ nn,
                            int D) {
  const int row  = blockIdx.x * 4 + (threadIdx.x >> 6);
  const int lane = threadIdx.x & 63;
  const float* src; u16* dst; float* nrm;
  if (blockIdx.y == 0)      { src = A;  dst = Ab; nrm = an; }
  else if (blockIdx.y == 1) { src = P;  dst = Pb; nrm = pn; }
  else                      { src = Ng; dst = Nb; nrm = nn; }
  float4 v = *(const float4*)(src + (size_t)row * D + lane * 4);
  float ss = v.x * v.x + v.y * v.y + v.z * v.z + v.w * v.w;
  ushort4 o = make_ushort4(f2bf_rne(v.x), f2bf_rne(v.y), f2bf_rne(v.z), f2bf_rne(v.w));
  *(ushort4*)(dst + (size_t)row * D + lane * 4) = o;
  #pragma unroll
  for (int m = 1; m < 64; m <<= 1) ss += __shfl_xor(ss, m);
  if (lane == 0) nrm[row] = ss;
}

__global__ void cvt_tgt_kernel(const int* __restrict__ t, int* __restrict__ cls, int N) {
  int i = blockIdx.x * 256 + threadIdx.x;
  if (i < N) cls[i] = t[i];
}

__global__ void zero_kernel(float* out) { out[0] = 0.f; }

// ---------------- staging: 128 rows x 64 bf16 of g[rbase..][kb*64..] -> LDS -----
// LDS dest is linear (lane-ordered, required by global_load_lds); the XOR swizzle
// (byte ^= (row&7)<<4) is realized by pre-swizzling the per-lane GLOBAL source.
__device__ __forceinline__ void stage_tile(const u16* __restrict__ g, u16* lds,
                                           int rbase, int kb, int D, int w, int l) {
  #pragma unroll
  for (int c = 0; c < 4; ++c) {
    const int row  = w * 32 + c * 8 + (l >> 3);   // 8 lanes cover one 128B row
    const int slot = (l & 7) ^ (row & 7);         // inverse of read-side swizzle
    const u16* gp = g + (size_t)(rbase + row) * D + kb * 64 + slot * 8;
    u16* lp = lds + w * 2048 + c * 512;           // wave-uniform base; HW adds lane*16B
    __builtin_amdgcn_global_load_lds((const __attribute__((address_space(1))) void*)gp,
                                     (__attribute__((address_space(3))) void*)lp,
                                     16, 0, 0);
  }
}

// ---------------- main fused kernel -------------------------------------------
// 128x128 output tile, 4 waves (2x2), K=256 in 4 steps of BK=64.
// Computes partial (per column-tile) masked max/min of (colnorm - 2*dot).
__global__ __launch_bounds__(256, 2) void triplet_tile_kernel(
    const u16* __restrict__ Ab, const u16* __restrict__ Pb, const u16* __restrict__ Nb,
    const float* __restrict__ pnorm, const float* __restrict__ nnorm,
    const int* __restrict__ cls,
    float* __restrict__ maxP, float* __restrict__ minN, int N, int D) {
  __shared__ __align__(16) u16 As[128 * 64];
  __shared__ __align__(16) u16 Ps[128 * 64];
  __shared__ __align__(16) u16 Ns[128 * 64];
  __shared__ float pnS[128], nnS[128];
  __shared__ int   ccS[128], rcS[128];
  __shared__ float redP[2][128], redN[2][128];

  const int cb = blockIdx.x, rb = blockIdx.y;
  const int rowbase = rb * 128, colbase = cb * 128;
  const int t = threadIdx.x, l = t & 63, w = t >> 6;
  const int wr = w >> 1, wc = w & 1, g = l >> 4, lr = l & 15;

  if (t < 128) {
    pnS[t] = pnorm[colbase + t];
    nnS[t] = nnorm[colbase + t];
    ccS[t] = cls[colbase + t];
  } else {
    rcS[t - 128] = cls[rowbase + (t - 128)];
  }

  f32x4 accP[4][4], accN[4][4];
  #pragma unroll
  for (int m = 0; m < 4; ++m)
    #pragma unroll
    for (int n = 0; n < 4; ++n) {
      accP[m][n] = (f32x4){0.f, 0.f, 0.f, 0.f};
      accN[m][n] = (f32x4){0.f, 0.f, 0.f, 0.f};
    }

  const int nKB = D / 64;
  for (int kb = 0; kb < nKB; ++kb) {
    __syncthreads();                       // previous tile fully consumed
    stage_tile(Ab, As, rowbase, kb, D, w, l);
    stage_tile(Pb, Ps, colbase, kb, D, w, l);
    stage_tile(Nb, Ns, colbase, kb, D, w, l);
    __syncthreads();                       // drains vmcnt -> LDS data visible
    #pragma unroll
    for (int kk = 0; kk < 2; ++kk) {
      bf16x8 af[4], bp[4], bn[4];
      #pragma unroll
      for (int m = 0; m < 4; ++m) {
        const int row  = wr * 64 + m * 16 + lr;
        const int slot = (kk * 4 + g) ^ (row & 7);
        af[m] = *(const bf16x8*)&As[row * 64 + slot * 8];
      }
      #pragma unroll
      for (int n = 0; n < 4; ++n) {
        const int col  = wc * 64 + n * 16 + lr;
        const int slot = (kk * 4 + g) ^ (col & 7);
        bp[n] = *(const bf16x8*)&Ps[col * 64 + slot * 8];
        bn[n] = *(const bf16x8*)&Ns[col * 64 + slot * 8];
      }
      #pragma unroll
      for (int m = 0; m < 4; ++m)
        #pragma unroll
        for (int n = 0; n < 4; ++n) {
          accP[m][n] = __builtin_amdgcn_mfma_f32_16x16x32_bf16(af[m], bp[n], accP[m][n], 0, 0, 0);
          accN[m][n] = __builtin_amdgcn_mfma_f32_16x16x32_bf16(af[m], bn[n], accN[m][n], 0, 0, 0);
        }
    }
  }

  // Epilogue: masked row max/min on (colnorm - 2*dot); C/D layout:
  // col = lane&15, row = (lane>>4)*4 + reg  [measured m89/m91]
  #pragma unroll
  for (int m = 0; m < 4; ++m) {
    #pragma unroll
    for (int r = 0; r < 4; ++r) {
      const int row = wr * 64 + m * 16 + g * 4 + r;
      const int rc  = rcS[row];
      float vmax = NEG_INF, vmin = POS_INF;
      #pragma unroll
      for (int n = 0; n < 4; ++n) {
        const int col = wc * 64 + n * 16 + lr;
        const bool same = (rc == ccS[col]);
        const float vp = fmaf(-2.f, accP[m][n][r], pnS[col]);
        const float vn = fmaf(-2.f, accN[m][n][r], nnS[col]);
        vmax = same ? fmaxf(vmax, vp) : vmax;
        vmin = same ? vmin : fminf(vmin, vn);
      }
      #pragma unroll
      for (int msk = 1; msk < 16; msk <<= 1) {
        vmax = fmaxf(vmax, __shfl_xor(vmax, msk));
        vmin = fminf(vmin, __shfl_xor(vmin, msk));
      }
      if (lr == 0) { redP[wc][row] = vmax; redN[wc][row] = vmin; }
    }
  }
  __syncthreads();
  if (t < 128) {
    const float mx = fmaxf(redP[0][t], redP[1][t]);
    const float mn = fminf(redN[0][t], redN[1][t]);
    maxP[(size_t)cb * N + rowbase + t] = mx;
    minN[(size_t)cb * N + rowbase + t] = mn;
  }
}

// ---------------- finalize: combine partials, loss, mean ----------------------
__global__ void finalize_kernel(const float* __restrict__ maxP, const float* __restrict__ minN,
                                const float* __restrict__ an, float* out, int N, int nCB) {
  const int r = blockIdx.x * 128 + threadIdx.x;
  float mx = NEG_INF, mn = POS_INF;
  for (int cb = 0; cb < nCB; ++cb) {
    mx = fmaxf(mx, maxP[(size_t)cb * N + r]);
    mn = fminf(mn, minN[(size_t)cb * N + r]);
  }
  const float a  = an[r];
  const float dp = sqrtf(fmaxf(a + mx, 1e-12f));
  const float dn = sqrtf(fmaxf(a + mn, 1e-12f));
  float loss = fmaxf(dp - dn + MARGIN, 0.f);
  #pragma unroll
  for (int msk = 1; msk < 64; msk <<= 1) loss += __shfl_xor(loss, msk);
  __shared__ float s[2];
  if ((threadIdx.x & 63) == 0) s[threadIdx.x >> 6] = loss;
  __syncthreads();
  if (threadIdx.x == 0) atomicAdd(out, (s[0] + s[1]) * (1.0f / N));
}

extern "C" void kernel_launch(void* const* d_in, const int* in_sizes, int n_in,
                              void* d_out, int out_size, void* d_ws, size_t ws_size,
                              hipStream_t stream) {
  const float* A  = (const float*)d_in[0];
  const float* P  = (const float*)d_in[1];
  const float* Ng = (const float*)d_in[2];
  const int*   tg = (const int*)d_in[3];
  float* out = (float*)d_out;

  const int N = in_sizes[3];        // 8192
  const int D = in_sizes[0] / N;    // 256
  const int nRB = N / 128, nCB = N / 128;

  char* ws = (char*)d_ws;
  const size_t bf = (size_t)N * D * sizeof(u16);
  u16* Ab = (u16*)ws;
  u16* Pb = (u16*)(ws + bf);
  u16* Nb = (u16*)(ws + 2 * bf);
  char* p = ws + 3 * bf;
  float* an = (float*)p; p += (size_t)N * 4;
  float* pn = (float*)p; p += (size_t)N * 4;
  float* nn = (float*)p; p += (size_t)N * 4;
  int*  cls = (int*)p;   p += (size_t)N * 4;
  float* maxP = (float*)p; p += (size_t)nCB * N * 4;
  float* minN = (float*)p;

  zero_kernel<<<1, 1, 0, stream>>>(out);
  prep_kernel<<<dim3(N / 4, 3), 256, 0, stream>>>(A, P, Ng, Ab, Pb, Nb, an, pn, nn, D);
  cvt_tgt_kernel<<<(N + 255) / 256, 256, 0, stream>>>(tg, cls, N);
  triplet_tile_kernel<<<dim3(nCB, nRB), 256, 0, stream>>>(Ab, Pb, Nb, pn, nn, cls, maxP, minN, N, D);
  finalize_kernel<<<N / 128, 128, 0, stream>>>(maxP, minN, an, out, N, nCB);
}